// Round 2
// baseline (1294.776 us; speedup 1.0000x reference)
//
#include <hip/hip_runtime.h>
#include <hip/hip_bf16.h>
#include <hip/hip_fp16.h>

typedef __hip_bfloat16 bf16;

#define BATCH 4
#define SEQ   1024
#define DIM   1024
#define HEADS 16
#define HD    64
#define SCALE 0.125f   // HD^-0.5

// ---------------------------------------------------------------------------
// Dtype sniffer: if x (first 8192 16-bit words) contains bf16 NaN/Inf bit
// patterns, the buffer is really fp32 -> flag=1. Pristine bf16 normals: flag=0.
// ---------------------------------------------------------------------------
__global__ __launch_bounds__(256)
void sniff_dtype(const unsigned short* __restrict__ xu, int* __restrict__ flag)
{
    __shared__ int cnt;
    if (threadIdx.x == 0) cnt = 0;
    __syncthreads();
    int local = 0;
    for (int i = threadIdx.x; i < 8192; i += 256) {
        unsigned short u = xu[i];
        if ((u & 0x7FFF) >= 0x7F80) local++;   // bf16 NaN or Inf pattern
    }
    if (local) atomicAdd(&cnt, local);
    __syncthreads();
    if (threadIdx.x == 0) *flag = (cnt > 0) ? 1 : 0;   // 1 => inputs are fp32
}

// ---------------------------------------------------------------------------
// Projection GEMM: C[M,N] = A[M,K] @ W[N,K]^T + bias, fp32 accum,
// written as fp16 into [b*h, n, d] layout. Templated on input dtype; the
// whole grid early-returns if the sniffed flag doesn't match F32.
// ---------------------------------------------------------------------------
template<int F32>
__global__ __launch_bounds__(256)
void gemm_proj(const int* __restrict__ flag,
               const void* __restrict__ Av, const void* __restrict__ Wv,
               const void* __restrict__ biasv, __half* __restrict__ dstH)
{
    if (*flag != F32) return;

    const int K = DIM;
    __shared__ float As[64][33];
    __shared__ float Ws[64][33];

    const int m0 = blockIdx.y * 64;
    const int n0 = blockIdx.x * 64;
    const int tx = threadIdx.x;          // 0..15
    const int ty = threadIdx.y;          // 0..15
    const int t  = ty * 16 + tx;

    float acc[4][4] = {};

    for (int k0 = 0; k0 < K; k0 += 32) {
        __syncthreads();
        for (int idx = t; idx < 64 * 32; idx += 256) {
            int r = idx >> 5, c = idx & 31;
            size_t ia = (size_t)(m0 + r) * K + k0 + c;
            size_t iw = (size_t)(n0 + r) * K + k0 + c;
            As[r][c] = F32 ? ((const float*)Av)[ia]
                           : __bfloat162float(((const bf16*)Av)[ia]);
            Ws[r][c] = F32 ? ((const float*)Wv)[iw]
                           : __bfloat162float(((const bf16*)Wv)[iw]);
        }
        __syncthreads();
        const int ra = ty * 4;
        const int cb = tx * 4;
        #pragma unroll
        for (int k = 0; k < 32; ++k) {
            float a0 = As[ra + 0][k], a1 = As[ra + 1][k];
            float a2 = As[ra + 2][k], a3 = As[ra + 3][k];
            float b0 = Ws[cb + 0][k], b1 = Ws[cb + 1][k];
            float b2 = Ws[cb + 2][k], b3 = Ws[cb + 3][k];
            acc[0][0] += a0 * b0; acc[0][1] += a0 * b1; acc[0][2] += a0 * b2; acc[0][3] += a0 * b3;
            acc[1][0] += a1 * b0; acc[1][1] += a1 * b1; acc[1][2] += a1 * b2; acc[1][3] += a1 * b3;
            acc[2][0] += a2 * b0; acc[2][1] += a2 * b1; acc[2][2] += a2 * b2; acc[2][3] += a2 * b3;
            acc[3][0] += a3 * b0; acc[3][1] += a3 * b1; acc[3][2] += a3 * b2; acc[3][3] += a3 * b3;
        }
    }

    const int rbase = m0 + ty * 4;
    const int cbase = n0 + tx * 4;
    #pragma unroll
    for (int i = 0; i < 4; ++i) {
        #pragma unroll
        for (int j = 0; j < 4; ++j) {
            const int m  = rbase + i;
            const int nn = cbase + j;
            float bv = F32 ? ((const float*)biasv)[nn]
                           : __bfloat162float(((const bf16*)biasv)[nn]);
            float val = acc[i][j] + bv;
            int bb = m >> 10, ii = m & 1023;
            int head = nn >> 6, dd = nn & 63;
            dstH[((size_t)(bb * HEADS + head) * SEQ + ii) * HD + dd] = __float2half(val);
        }
    }
}

// ---------------------------------------------------------------------------
// Output GEMM: out[M,N] = Oh[M,K] @ Wo[N,K]^T + bo. Oh is fp16 in [M,K]
// row-major ([b, n, h*d]). Output dtype follows the flag.
// ---------------------------------------------------------------------------
template<int F32>
__global__ __launch_bounds__(256)
void gemm_out(const int* __restrict__ flag,
              const __half* __restrict__ Ah, const void* __restrict__ Wv,
              const void* __restrict__ biasv, void* __restrict__ outv)
{
    if (*flag != F32) return;

    const int K = DIM;
    __shared__ float As[64][33];
    __shared__ float Ws[64][33];

    const int m0 = blockIdx.y * 64;
    const int n0 = blockIdx.x * 64;
    const int tx = threadIdx.x;
    const int ty = threadIdx.y;
    const int t  = ty * 16 + tx;

    float acc[4][4] = {};

    for (int k0 = 0; k0 < K; k0 += 32) {
        __syncthreads();
        for (int idx = t; idx < 64 * 32; idx += 256) {
            int r = idx >> 5, c = idx & 31;
            size_t ia = (size_t)(m0 + r) * K + k0 + c;
            size_t iw = (size_t)(n0 + r) * K + k0 + c;
            As[r][c] = __half2float(Ah[ia]);
            Ws[r][c] = F32 ? ((const float*)Wv)[iw]
                           : __bfloat162float(((const bf16*)Wv)[iw]);
        }
        __syncthreads();
        const int ra = ty * 4;
        const int cb = tx * 4;
        #pragma unroll
        for (int k = 0; k < 32; ++k) {
            float a0 = As[ra + 0][k], a1 = As[ra + 1][k];
            float a2 = As[ra + 2][k], a3 = As[ra + 3][k];
            float b0 = Ws[cb + 0][k], b1 = Ws[cb + 1][k];
            float b2 = Ws[cb + 2][k], b3 = Ws[cb + 3][k];
            acc[0][0] += a0 * b0; acc[0][1] += a0 * b1; acc[0][2] += a0 * b2; acc[0][3] += a0 * b3;
            acc[1][0] += a1 * b0; acc[1][1] += a1 * b1; acc[1][2] += a1 * b2; acc[1][3] += a1 * b3;
            acc[2][0] += a2 * b0; acc[2][1] += a2 * b1; acc[2][2] += a2 * b2; acc[2][3] += a2 * b3;
            acc[3][0] += a3 * b0; acc[3][1] += a3 * b1; acc[3][2] += a3 * b2; acc[3][3] += a3 * b3;
        }
    }

    const int rbase = m0 + ty * 4;
    const int cbase = n0 + tx * 4;
    #pragma unroll
    for (int i = 0; i < 4; ++i) {
        #pragma unroll
        for (int j = 0; j < 4; ++j) {
            const int m  = rbase + i;
            const int nn = cbase + j;
            float bv = F32 ? ((const float*)biasv)[nn]
                           : __bfloat162float(((const bf16*)biasv)[nn]);
            float val = acc[i][j] + bv;
            size_t oi = (size_t)m * DIM + nn;
            if (F32) ((float*)outv)[oi] = val;
            else     ((bf16*)outv)[oi] = __float2bfloat16(val);
        }
    }
}

// ---------------------------------------------------------------------------
// Flash-style L2 attention. Row constant -||qi||^2 cancels in softmax ->
// s' = (2 qi.qj - ||qj||^2)*SCALE. Q,V fp16 [B*H, SEQ, HD]; O fp16
// [B, SEQ, DIM] (b n (h d)). 256 threads, i-tile 32, j-tile 64.
// ---------------------------------------------------------------------------
__global__ __launch_bounds__(256)
void attn_l2(const __half* __restrict__ Q, const __half* __restrict__ V,
             __half* __restrict__ O)
{
    __shared__ float q_s[32][65];
    __shared__ float k_s[64][65];
    __shared__ float v_s[64][64];
    __shared__ float s_s[32][65];
    __shared__ float sqj[64];
    __shared__ float m_s[32], l_s[32], al_s[32];

    const int bh = blockIdx.y;
    const int i0 = blockIdx.x * 32;
    const __half* __restrict__ Qh = Q + (size_t)bh * SEQ * HD;
    const __half* __restrict__ Vh = V + (size_t)bh * SEQ * HD;
    const int t = threadIdx.x;

    for (int idx = t; idx < 32 * 64; idx += 256) {
        int r = idx >> 6, c = idx & 63;
        q_s[r][c] = __half2float(Qh[(size_t)(i0 + r) * HD + c]);
    }
    if (t < 32) { m_s[t] = -1e30f; l_s[t] = 0.f; }

    float acc[2][4] = {};
    const int r0 = (t >> 4) * 2;   // 0,2,..,30
    const int c0 = (t & 15) * 4;   // 0,4,..,60

    for (int jt = 0; jt < SEQ / 64; ++jt) {
        const int j0 = jt * 64;
        __syncthreads();
        for (int idx = t; idx < 64 * 64; idx += 256) {
            int r = idx >> 6, c = idx & 63;
            k_s[r][c] = __half2float(Qh[(size_t)(j0 + r) * HD + c]);
            v_s[r][c] = __half2float(Vh[(size_t)(j0 + r) * HD + c]);
        }
        __syncthreads();
        if (t < 64) {
            float s = 0.f;
            #pragma unroll
            for (int c = 0; c < 64; ++c) { float x = k_s[t][c]; s += x * x; }
            sqj[t] = s;
        }
        __syncthreads();

        float sc[2][4] = {};
        #pragma unroll
        for (int dd = 0; dd < 64; ++dd) {
            float qa = q_s[r0][dd], qb = q_s[r0 + 1][dd];
            float k0v = k_s[c0 + 0][dd], k1v = k_s[c0 + 1][dd];
            float k2v = k_s[c0 + 2][dd], k3v = k_s[c0 + 3][dd];
            sc[0][0] += qa * k0v; sc[0][1] += qa * k1v; sc[0][2] += qa * k2v; sc[0][3] += qa * k3v;
            sc[1][0] += qb * k0v; sc[1][1] += qb * k1v; sc[1][2] += qb * k2v; sc[1][3] += qb * k3v;
        }
        #pragma unroll
        for (int ji = 0; ji < 4; ++ji) {
            float sq = sqj[c0 + ji];
            s_s[r0 + 0][c0 + ji] = (2.f * sc[0][ji] - sq) * SCALE;
            s_s[r0 + 1][c0 + ji] = (2.f * sc[1][ji] - sq) * SCALE;
        }
        __syncthreads();

        if (t < 32) {
            float m_old = m_s[t];
            float mt = m_old;
            #pragma unroll
            for (int j = 0; j < 64; ++j) mt = fmaxf(mt, s_s[t][j]);
            float alpha = __expf(m_old - mt);
            float sum = 0.f;
            #pragma unroll
            for (int j = 0; j < 64; ++j) {
                float p = __expf(s_s[t][j] - mt);
                s_s[t][j] = p;
                sum += p;
            }
            l_s[t] = l_s[t] * alpha + sum;
            m_s[t] = mt;
            al_s[t] = alpha;
        }
        __syncthreads();

        const float a0 = al_s[r0], a1 = al_s[r0 + 1];
        #pragma unroll
        for (int ci = 0; ci < 4; ++ci) { acc[0][ci] *= a0; acc[1][ci] *= a1; }
        #pragma unroll
        for (int j = 0; j < 64; ++j) {
            float p0 = s_s[r0][j], p1 = s_s[r0 + 1][j];
            float v0 = v_s[j][c0 + 0], v1 = v_s[j][c0 + 1];
            float v2 = v_s[j][c0 + 2], v3 = v_s[j][c0 + 3];
            acc[0][0] += p0 * v0; acc[0][1] += p0 * v1; acc[0][2] += p0 * v2; acc[0][3] += p0 * v3;
            acc[1][0] += p1 * v0; acc[1][1] += p1 * v1; acc[1][2] += p1 * v2; acc[1][3] += p1 * v3;
        }
    }

    const int bb = bh >> 4, head = bh & 15;
    const float inv0 = 1.f / l_s[r0];
    const float inv1 = 1.f / l_s[r0 + 1];
    #pragma unroll
    for (int ci = 0; ci < 4; ++ci) {
        size_t o0 = ((size_t)(bb * SEQ + i0 + r0 + 0)) * DIM + head * HD + c0 + ci;
        size_t o1 = ((size_t)(bb * SEQ + i0 + r0 + 1)) * DIM + head * HD + c0 + ci;
        O[o0] = __float2half(acc[0][ci] * inv0);
        O[o1] = __float2half(acc[1][ci] * inv1);
    }
}

extern "C" void kernel_launch(void* const* d_in, const int* in_sizes, int n_in,
                              void* d_out, int out_size, void* d_ws, size_t ws_size,
                              hipStream_t stream)
{
    // ws layout: [0..255] flag page | Qh fp16 8MB | Vh fp16 8MB | Oh fp16 8MB
    int*    flag = (int*)d_ws;
    __half* Qh   = (__half*)((char*)d_ws + 256);
    __half* Vh   = Qh + (size_t)BATCH * HEADS * SEQ * HD;
    __half* Oh   = Vh + (size_t)BATCH * HEADS * SEQ * HD;

    dim3 gthr(16, 16);
    dim3 ggrid(DIM / 64, (BATCH * SEQ) / 64);   // (16, 64)
    dim3 agrid(SEQ / 32, BATCH * HEADS);        // (32, 64)

    sniff_dtype<<<1, 256, 0, stream>>>((const unsigned short*)d_in[0], flag);

    gemm_proj<0><<<ggrid, gthr, 0, stream>>>(flag, d_in[0], d_in[1], d_in[2], Qh);
    gemm_proj<1><<<ggrid, gthr, 0, stream>>>(flag, d_in[0], d_in[1], d_in[2], Qh);
    gemm_proj<0><<<ggrid, gthr, 0, stream>>>(flag, d_in[0], d_in[3], d_in[4], Vh);
    gemm_proj<1><<<ggrid, gthr, 0, stream>>>(flag, d_in[0], d_in[3], d_in[4], Vh);

    attn_l2<<<agrid, 256, 0, stream>>>(Qh, Vh, Oh);

    gemm_out<0><<<ggrid, gthr, 0, stream>>>(flag, Oh, d_in[5], d_in[6], d_out);
    gemm_out<1><<<ggrid, gthr, 0, stream>>>(flag, Oh, d_in[5], d_in[6], d_out);
}

// Round 5
// 256.209 us; speedup vs baseline: 5.0536x; 5.0536x over previous
//
#include <hip/hip_runtime.h>
#include <hip/hip_bf16.h>

typedef __hip_bfloat16 bf16;
typedef short short8 __attribute__((ext_vector_type(8)));
typedef float floatx4 __attribute__((ext_vector_type(4)));

#define MFMA16x16x32 __builtin_amdgcn_mfma_f32_16x16x32_bf16

#define BATCH 4
#define SEQ   1024
#define DIM   1024
#define HEADS 16
#define HD    64
// scores = -(sq_i - 2 q.k + sq_j) * 0.125; row const sq_i cancels in softmax
// -> s' = 0.25*dot - 0.125*sq_j

#define RS 40   // LDS row stride in shorts (80 B): bank stride 20 -> worst 2-way (free)

__device__ __forceinline__ float b2f(unsigned short u) {
    union { unsigned int i; float f; } x; x.i = ((unsigned int)u) << 16; return x.f;
}
__device__ __forceinline__ unsigned short f2b(float f) {
    union { float f; unsigned int i; } x; x.f = f;
    unsigned int r = (x.i + 0x7FFFu + ((x.i >> 16) & 1u)) >> 16;
    return (unsigned short)r;
}

// load 8 contiguous elements as bf16 bits, converting from fp32 if needed
template<int SRC_F32>
__device__ __forceinline__ short8 ld8(const void* p, size_t off) {
    if (SRC_F32) {
        const float* f = (const float*)p + off;
        float4 a = *(const float4*)f;
        float4 b = *(const float4*)(f + 4);
        short8 r;
        r[0] = (short)f2b(a.x); r[1] = (short)f2b(a.y);
        r[2] = (short)f2b(a.z); r[3] = (short)f2b(a.w);
        r[4] = (short)f2b(b.x); r[5] = (short)f2b(b.y);
        r[6] = (short)f2b(b.z); r[7] = (short)f2b(b.w);
        return r;
    } else {
        return *(const short8*)((const unsigned short*)p + off);
    }
}

// ---------------------------------------------------------------------------
// Dtype sniffer (proven in round 2): fp32 buffers read as 16-bit halves show
// bf16 NaN/Inf patterns (~0.4% of low halves); true bf16 normals show none.
// ---------------------------------------------------------------------------
__global__ __launch_bounds__(256)
void sniff_dtype(const unsigned short* __restrict__ xu, int* __restrict__ flag)
{
    __shared__ int cnt;
    if (threadIdx.x == 0) cnt = 0;
    __syncthreads();
    int local = 0;
    for (int i = threadIdx.x; i < 8192; i += 256) {
        unsigned short u = xu[i];
        if ((u & 0x7FFF) >= 0x7F80) local++;
    }
    if (local) atomicAdd(&cnt, local);
    __syncthreads();
    if (threadIdx.x == 0) *flag = (cnt > 0) ? 1 : 0;   // 1 => fp32 inputs
}

// ---------------------------------------------------------------------------
// MFMA GEMM: C[M=4096,N=1024] = A[M,K=1024] @ W[N,K]^T + bias
// 128x64 tile, BK=32, 4 waves, wave = 64x32 (4x2 MFMA 16x16x32 tiles).
// F32 = sniffed dtype this variant serves (gates whole grid; also W/bias/out
// dtype). AF32 = A operand's dtype (x follows flag; Oh scratch is always bf16).
// mode 0: dst bf16 [b*h, n, d] (Q/V projections); mode 1: dst [M,N], dtype=F32.
// ---------------------------------------------------------------------------
template<int F32, int AF32>
__global__ __launch_bounds__(256)
void gemm_mfma(const int* __restrict__ flag,
               const void* __restrict__ Av, const void* __restrict__ Wmat,
               const void* __restrict__ biasv, void* __restrict__ dstv, int mode)
{
    if (*flag != F32) return;

    __shared__ __align__(16) unsigned short Asm[128 * RS];
    __shared__ __align__(16) unsigned short Bsm[64 * RS];

    const int t = threadIdx.x;
    const int w = t >> 6, lane = t & 63;
    const int lr = lane & 15, quad = lane >> 4;
    const int m0 = blockIdx.y * 128, n0 = blockIdx.x * 64;
    const int mw = (w >> 1) * 64;
    const int nw = (w & 1) * 32;

    floatx4 acc[4][2];
    const floatx4 fz = {0.f, 0.f, 0.f, 0.f};
    #pragma unroll
    for (int i = 0; i < 4; ++i)
        #pragma unroll
        for (int j = 0; j < 2; ++j) acc[i][j] = fz;

    for (int k0 = 0; k0 < DIM; k0 += 32) {
        __syncthreads();
        #pragma unroll
        for (int it = 0; it < 2; ++it) {               // A tile: 128x32
            const int idx = it * 256 + t;
            const int r = idx >> 2, c8 = (idx & 3) * 8;
            *(short8*)&Asm[r * RS + c8] = ld8<AF32>(Av, (size_t)(m0 + r) * DIM + k0 + c8);
        }
        {                                               // B tile: 64x32
            const int r = t >> 2, c8 = (t & 3) * 8;
            *(short8*)&Bsm[r * RS + c8] = ld8<F32>(Wmat, (size_t)(n0 + r) * DIM + k0 + c8);
        }
        __syncthreads();

        short8 af[4], bfr[2];
        #pragma unroll
        for (int tm = 0; tm < 4; ++tm)
            af[tm] = *(const short8*)&Asm[(mw + tm * 16 + lr) * RS + quad * 8];
        #pragma unroll
        for (int tn = 0; tn < 2; ++tn)
            bfr[tn] = *(const short8*)&Bsm[(nw + tn * 16 + lr) * RS + quad * 8];
        #pragma unroll
        for (int tm = 0; tm < 4; ++tm)
            #pragma unroll
            for (int tn = 0; tn < 2; ++tn)
                acc[tm][tn] = MFMA16x16x32(af[tm], bfr[tn], acc[tm][tn], 0, 0, 0);
    }

    // epilogue: D layout col=lane&15, row=quad*4+reg [verified m89/m91]
    #pragma unroll
    for (int tm = 0; tm < 4; ++tm) {
        #pragma unroll
        for (int tn = 0; tn < 2; ++tn) {
            const int n = n0 + nw + tn * 16 + lr;
            const float bv = F32 ? ((const float*)biasv)[n]
                                 : __bfloat162float(((const bf16*)biasv)[n]);
            #pragma unroll
            for (int r = 0; r < 4; ++r) {
                const int m = m0 + mw + tm * 16 + quad * 4 + r;
                const float val = acc[tm][tn][r] + bv;
                if (mode == 0) {
                    const int bb = m >> 10, ii = m & 1023;
                    const int head = n >> 6, dd = n & 63;
                    ((bf16*)dstv)[((size_t)(bb * HEADS + head) * SEQ + ii) * HD + dd] =
                        __float2bfloat16(val);
                } else {
                    const size_t oi = (size_t)m * DIM + n;
                    if (F32) ((float*)dstv)[oi] = val;
                    else     ((bf16*)dstv)[oi] = __float2bfloat16(val);
                }
            }
        }
    }
}

// ---------------------------------------------------------------------------
// MFMA flash L2-attention (byte-identical to round 4; bf16 scratch in/out).
// ---------------------------------------------------------------------------
__global__ __launch_bounds__(256)
void attn_mfma(const bf16* __restrict__ Q, const bf16* __restrict__ V,
               bf16* __restrict__ O)
{
    __shared__ __align__(16) unsigned short Ks[64 * 72];
    __shared__ __align__(16) unsigned short Vt[64 * 72];
    __shared__ __align__(16) unsigned short Ps[128 * 72];
    __shared__ float sqs[64];

    const int t = threadIdx.x;
    const int w = t >> 6, lane = t & 63;
    const int lr = lane & 15, quad = lane >> 4;
    const int bh = blockIdx.y, i0 = blockIdx.x * 128;
    const bf16* __restrict__ Qp = Q + (size_t)bh * SEQ * HD;
    const bf16* __restrict__ Vp = V + (size_t)bh * SEQ * HD;

    #pragma unroll
    for (int it = 0; it < 4; ++it) {
        const int idx = it * 256 + t;
        const int r = idx >> 3, c8 = (idx & 7) * 8;
        *(uint4*)&Ps[r * 72 + c8] = *(const uint4*)(Qp + (size_t)(i0 + r) * HD + c8);
    }
    __syncthreads();
    short8 qa[2][2];
    #pragma unroll
    for (int tm = 0; tm < 2; ++tm)
        #pragma unroll
        for (int ks = 0; ks < 2; ++ks)
            qa[tm][ks] = *(const short8*)&Ps[(w * 32 + tm * 16 + lr) * 72 + ks * 32 + quad * 8];

    floatx4 oacc[2][4];
    const floatx4 fz = {0.f, 0.f, 0.f, 0.f};
    float mrow[2][4], lrow[2][4];
    #pragma unroll
    for (int tm = 0; tm < 2; ++tm) {
        #pragma unroll
        for (int td = 0; td < 4; ++td) oacc[tm][td] = fz;
        #pragma unroll
        for (int r = 0; r < 4; ++r) { mrow[tm][r] = -1e30f; lrow[tm][r] = 0.f; }
    }

    for (int jt = 0; jt < 16; ++jt) {
        const int j0 = jt * 64;
        __syncthreads();
        #pragma unroll
        for (int it = 0; it < 2; ++it) {
            const int idx = it * 256 + t;
            const int r = idx >> 3, c8 = (idx & 7) * 8;
            *(uint4*)&Ks[r * 72 + c8] = *(const uint4*)(Qp + (size_t)(j0 + r) * HD + c8);
            *(uint4*)&Ps[r * 72 + c8] = *(const uint4*)(Vp + (size_t)(j0 + r) * HD + c8);
        }
        __syncthreads();

        #pragma unroll
        for (int it = 0; it < 2; ++it) {
            const int j = t & 63, c0 = w * 8 + it * 32;
            uint4 pv = *(const uint4*)&Ps[j * 72 + c0];
            const unsigned short* u = (const unsigned short*)&pv;
            #pragma unroll
            for (int cc = 0; cc < 8; ++cc)
                Vt[(c0 + cc) * 72 + j] = u[cc];
        }
        {
            const int jr = w * 16 + lr, ch = quad * 16;
            uint4 k1 = *(const uint4*)&Ks[jr * 72 + ch];
            uint4 k2 = *(const uint4*)&Ks[jr * 72 + ch + 8];
            const unsigned short* u1 = (const unsigned short*)&k1;
            const unsigned short* u2 = (const unsigned short*)&k2;
            float s = 0.f;
            #pragma unroll
            for (int cc = 0; cc < 8; ++cc) {
                float f1 = b2f(u1[cc]), f2 = b2f(u2[cc]);
                s += f1 * f1 + f2 * f2;
            }
            s += __shfl_xor(s, 16);
            s += __shfl_xor(s, 32);
            if (quad == 0) sqs[jr] = s;
        }
        __syncthreads();

        short8 kb[4][2];
        #pragma unroll
        for (int tn = 0; tn < 4; ++tn)
            #pragma unroll
            for (int ks = 0; ks < 2; ++ks)
                kb[tn][ks] = *(const short8*)&Ks[(tn * 16 + lr) * 72 + ks * 32 + quad * 8];
        floatx4 sacc[2][4];
        #pragma unroll
        for (int tm = 0; tm < 2; ++tm)
            #pragma unroll
            for (int tn = 0; tn < 4; ++tn) {
                floatx4 a = MFMA16x16x32(qa[tm][0], kb[tn][0], fz, 0, 0, 0);
                sacc[tm][tn] = MFMA16x16x32(qa[tm][1], kb[tn][1], a, 0, 0, 0);
            }

        float sq4[4];
        #pragma unroll
        for (int tn = 0; tn < 4; ++tn) sq4[tn] = sqs[tn * 16 + lr];

        #pragma unroll
        for (int tm = 0; tm < 2; ++tm) {
            float sc[4][4];
            #pragma unroll
            for (int tn = 0; tn < 4; ++tn)
                #pragma unroll
                for (int r = 0; r < 4; ++r)
                    sc[tn][r] = 0.25f * sacc[tm][tn][r] - 0.125f * sq4[tn];
            #pragma unroll
            for (int r = 0; r < 4; ++r) {
                float vm = fmaxf(fmaxf(sc[0][r], sc[1][r]), fmaxf(sc[2][r], sc[3][r]));
                vm = fmaxf(vm, __shfl_xor(vm, 1));
                vm = fmaxf(vm, __shfl_xor(vm, 2));
                vm = fmaxf(vm, __shfl_xor(vm, 4));
                vm = fmaxf(vm, __shfl_xor(vm, 8));
                const float mnew = fmaxf(mrow[tm][r], vm);
                const float alpha = __expf(mrow[tm][r] - mnew);
                mrow[tm][r] = mnew;
                float rs = 0.f;
                #pragma unroll
                for (int tn = 0; tn < 4; ++tn) {
                    float p = __expf(sc[tn][r] - mnew);
                    sc[tn][r] = p;
                    rs += p;
                }
                rs += __shfl_xor(rs, 1);
                rs += __shfl_xor(rs, 2);
                rs += __shfl_xor(rs, 4);
                rs += __shfl_xor(rs, 8);
                lrow[tm][r] = lrow[tm][r] * alpha + rs;
                #pragma unroll
                for (int td = 0; td < 4; ++td)
                    oacc[tm][td][r] *= alpha;
            }
            #pragma unroll
            for (int tn = 0; tn < 4; ++tn)
                #pragma unroll
                for (int r = 0; r < 4; ++r)
                    Ps[(w * 32 + tm * 16 + quad * 4 + r) * 72 + tn * 16 + lr] = f2b(sc[tn][r]);
        }
        __syncthreads();

        short8 pa[2][2], vb[4][2];
        #pragma unroll
        for (int tm = 0; tm < 2; ++tm)
            #pragma unroll
            for (int ks = 0; ks < 2; ++ks)
                pa[tm][ks] = *(const short8*)&Ps[(w * 32 + tm * 16 + lr) * 72 + ks * 32 + quad * 8];
        #pragma unroll
        for (int td = 0; td < 4; ++td)
            #pragma unroll
            for (int ks = 0; ks < 2; ++ks)
                vb[td][ks] = *(const short8*)&Vt[(td * 16 + lr) * 72 + ks * 32 + quad * 8];
        #pragma unroll
        for (int tm = 0; tm < 2; ++tm)
            #pragma unroll
            for (int td = 0; td < 4; ++td) {
                oacc[tm][td] = MFMA16x16x32(pa[tm][0], vb[td][0], oacc[tm][td], 0, 0, 0);
                oacc[tm][td] = MFMA16x16x32(pa[tm][1], vb[td][1], oacc[tm][td], 0, 0, 0);
            }
    }

    const int bb = bh >> 4, head = bh & 15;
    #pragma unroll
    for (int tm = 0; tm < 2; ++tm) {
        #pragma unroll
        for (int r = 0; r < 4; ++r) {
            const float inv = 1.f / lrow[tm][r];
            const int row = i0 + w * 32 + tm * 16 + quad * 4 + r;
            #pragma unroll
            for (int td = 0; td < 4; ++td) {
                const int col = head * HD + td * 16 + lr;
                O[(size_t)(bb * SEQ + row) * DIM + col] =
                    __float2bfloat16(oacc[tm][td][r] * inv);
            }
        }
    }
}

extern "C" void kernel_launch(void* const* d_in, const int* in_sizes, int n_in,
                              void* d_out, int out_size, void* d_ws, size_t ws_size,
                              hipStream_t stream)
{
    // ws: [0..255] flag page | Qh bf16 8MB | Vh bf16 8MB | Oh bf16 8MB  (proven 24MB+256)
    int* flag = (int*)d_ws;
    bf16* Qh = (bf16*)((char*)d_ws + 256);
    bf16* Vh = Qh + (size_t)BATCH * HEADS * SEQ * HD;
    bf16* Oh = Vh + (size_t)BATCH * HEADS * SEQ * HD;

    dim3 gg(DIM / 64, (BATCH * SEQ) / 128);   // (16, 32) = 512 blocks

    sniff_dtype<<<1, 256, 0, stream>>>((const unsigned short*)d_in[0], flag);

    gemm_mfma<0,0><<<gg, 256, 0, stream>>>(flag, d_in[0], d_in[1], d_in[2], Qh, 0);
    gemm_mfma<1,1><<<gg, 256, 0, stream>>>(flag, d_in[0], d_in[1], d_in[2], Qh, 0);
    gemm_mfma<0,0><<<gg, 256, 0, stream>>>(flag, d_in[0], d_in[3], d_in[4], Vh, 0);
    gemm_mfma<1,1><<<gg, 256, 0, stream>>>(flag, d_in[0], d_in[3], d_in[4], Vh, 0);

    attn_mfma<<<dim3(SEQ / 128, BATCH * HEADS), 256, 0, stream>>>(Qh, Vh, Oh);

    gemm_mfma<0,0><<<gg, 256, 0, stream>>>(flag, Oh, d_in[5], d_in[6], d_out, 1);
    gemm_mfma<1,0><<<gg, 256, 0, stream>>>(flag, Oh, d_in[5], d_in[6], d_out, 1);
}